// Round 1
// baseline (1291.731 us; speedup 1.0000x reference)
//
#include <hip/hip_runtime.h>

// AttnPool: scores = softmax(x @ w, axis=0)  (GLOBAL softmax over all N rows)
//           out[b] = sum_{i: batch_index[i]==b} scores[i] * x[i]
//
// Key identity: softmax max-subtraction cancels in the weighted-sum ratio:
//   out[b] = sum_{i in b} exp(s_i) x_i / sum_j exp(s_j)
// s ~ N(0,1) (w scaled 1/sqrt(dim)), max|s| ~ 5.5 over 1e6 -> exp() safe in fp32.
// batch_index is SORTED -> one block per segment, rows contiguous, no out atomics.

#define DIM 256
#define NSEG 4096

__global__ __launch_bounds__(256) void attnpool_acc(
    const float* __restrict__ x,
    const float* __restrict__ w,
    const int* __restrict__ bidx,
    int n,
    float* __restrict__ out,
    float* __restrict__ total)
{
    const int seg = blockIdx.x;

    __shared__ int s_lo, s_hi;
    if (threadIdx.x == 0) {
        int lo = 0, hi = n;
        while (lo < hi) { int m = (lo + hi) >> 1; if (bidx[m] < seg) lo = m + 1; else hi = m; }
        s_lo = lo;
    }
    if (threadIdx.x == 64) {
        int lo = 0, hi = n;
        while (lo < hi) { int m = (lo + hi) >> 1; if (bidx[m] <= seg) lo = m + 1; else hi = m; }
        s_hi = lo;
    }
    __syncthreads();
    const int start = s_lo, end = s_hi;

    const int wave = threadIdx.x >> 6;   // 4 waves/block, each takes rows stride-4
    const int lane = threadIdx.x & 63;   // lane l owns dims [4l, 4l+4)

    const float4 wv = reinterpret_cast<const float4*>(w)[lane];
    float4 acc = make_float4(0.f, 0.f, 0.f, 0.f);
    float sumexp = 0.f;

    for (int i = start + wave; i < end; i += 4) {
        const float4 xv = reinterpret_cast<const float4*>(x + (size_t)i * DIM)[lane];
        float d = xv.x * wv.x + xv.y * wv.y + xv.z * wv.z + xv.w * wv.w;
        // butterfly reduce across the 64-lane wave -> all lanes hold full dot
        #pragma unroll
        for (int off = 32; off > 0; off >>= 1) d += __shfl_xor(d, off, 64);
        const float e = __expf(d);
        sumexp += e;
        acc.x += e * xv.x; acc.y += e * xv.y; acc.z += e * xv.z; acc.w += e * xv.w;
    }

    // combine the 4 waves' partial sums in LDS
    __shared__ float4 s_acc[256];
    __shared__ float  s_sum[4];
    s_acc[threadIdx.x] = acc;
    if (lane == 0) s_sum[wave] = sumexp;   // sumexp is wave-uniform after butterfly
    __syncthreads();

    if (wave == 0) {
        float4 a = s_acc[lane];
        const float4 b = s_acc[64 + lane];
        const float4 c = s_acc[128 + lane];
        const float4 d4 = s_acc[192 + lane];
        a.x += b.x + c.x + d4.x;
        a.y += b.y + c.y + d4.y;
        a.z += b.z + c.z + d4.z;
        a.w += b.w + c.w + d4.w;
        reinterpret_cast<float4*>(out + (size_t)seg * DIM)[lane] = a;  // unnormalized
        if (lane == 0)
            atomicAdd(total, s_sum[0] + s_sum[1] + s_sum[2] + s_sum[3]);
    }
}

__global__ __launch_bounds__(256) void attnpool_scale(
    float* __restrict__ out, const float* __restrict__ total)
{
    const float inv = 1.0f / *total;
    const int idx = blockIdx.x * 256 + threadIdx.x;
    float4* p = reinterpret_cast<float4*>(out) + idx;
    float4 v = *p;
    v.x *= inv; v.y *= inv; v.z *= inv; v.w *= inv;
    *p = v;
}

extern "C" void kernel_launch(void* const* d_in, const int* in_sizes, int n_in,
                              void* d_out, int out_size, void* d_ws, size_t ws_size,
                              hipStream_t stream) {
    const float* x   = (const float*)d_in[0];
    const float* w   = (const float*)d_in[1];
    const int*  bidx = (const int*)d_in[2];
    const int n = in_sizes[2];          // N = 1,000,000 (in_sizes[0] is N*DIM)
    float* out   = (float*)d_out;       // [NSEG, DIM]
    float* total = (float*)d_ws;        // global sum-of-exp accumulator

    hipMemsetAsync(total, 0, sizeof(float), stream);  // ws is poisoned 0xAA each call
    attnpool_acc<<<NSEG, 256, 0, stream>>>(x, w, bidx, n, out, total);
    attnpool_scale<<<(NSEG * DIM / 4) / 256, 256, 0, stream>>>(out, total);
}

// Round 2
// 1246.551 us; speedup vs baseline: 1.0362x; 1.0362x over previous
//
#include <hip/hip_runtime.h>

// AttnPool: scores = softmax(x @ w, axis=0)  (GLOBAL softmax over all N rows)
//           out[b] = sum_{i: batch_index[i]==b} scores[i] * x[i]
//
// Identity: out[b] = sum_{i in b} exp(s_i) x_i / sum_j exp(s_j) — max-subtraction
// cancels; s ~ N(0,1) so exp() is fp32-safe (verified absmax 4.8e-7 in R1).
// batch_index SORTED -> one block per segment, rows contiguous, no out atomics.
//
// R2: 4-row unroll per wave iteration (4 loads in flight, 4 interleaved shuffle
// chains) + nontemporal x loads (x is streamed exactly once, 1.024 GB).

#define DIM 256
#define NSEG 4096

typedef float f4 __attribute__((ext_vector_type(4)));

__device__ __forceinline__ float wave_allreduce(float d) {
    #pragma unroll
    for (int off = 32; off > 0; off >>= 1) d += __shfl_xor(d, off, 64);
    return d;
}

__global__ __launch_bounds__(256) void attnpool_acc(
    const float* __restrict__ x,
    const float* __restrict__ w,
    const int* __restrict__ bidx,
    int n,
    float* __restrict__ out,
    float* __restrict__ total)
{
    const int seg = blockIdx.x;

    __shared__ int s_lo, s_hi;
    if (threadIdx.x == 0) {
        int lo = 0, hi = n;
        while (lo < hi) { int m = (lo + hi) >> 1; if (bidx[m] < seg) lo = m + 1; else hi = m; }
        s_lo = lo;
    }
    if (threadIdx.x == 64) {
        int lo = 0, hi = n;
        while (lo < hi) { int m = (lo + hi) >> 1; if (bidx[m] <= seg) lo = m + 1; else hi = m; }
        s_hi = lo;
    }
    __syncthreads();
    const int start = s_lo, end = s_hi;

    const int wave = threadIdx.x >> 6;   // 4 waves/block, rows strided by 4
    const int lane = threadIdx.x & 63;   // lane l owns dims [4l, 4l+4)

    const f4 wv = ((const f4*)w)[lane];
    f4 acc = (f4){0.f, 0.f, 0.f, 0.f};
    float sumexp = 0.f;

    int i = start + wave;
    // main loop: 4 rows per iteration -> 4 independent loads + 4 shuffle chains
    for (; i + 12 < end; i += 16) {
        const f4 x0 = __builtin_nontemporal_load((const f4*)(x + (size_t)(i     ) * DIM) + lane);
        const f4 x1 = __builtin_nontemporal_load((const f4*)(x + (size_t)(i +  4) * DIM) + lane);
        const f4 x2 = __builtin_nontemporal_load((const f4*)(x + (size_t)(i +  8) * DIM) + lane);
        const f4 x3 = __builtin_nontemporal_load((const f4*)(x + (size_t)(i + 12) * DIM) + lane);
        float d0 = x0.x*wv.x + x0.y*wv.y + x0.z*wv.z + x0.w*wv.w;
        float d1 = x1.x*wv.x + x1.y*wv.y + x1.z*wv.z + x1.w*wv.w;
        float d2 = x2.x*wv.x + x2.y*wv.y + x2.z*wv.z + x2.w*wv.w;
        float d3 = x3.x*wv.x + x3.y*wv.y + x3.z*wv.z + x3.w*wv.w;
        #pragma unroll
        for (int off = 32; off > 0; off >>= 1) {   // 4 independent chains interleave
            d0 += __shfl_xor(d0, off, 64);
            d1 += __shfl_xor(d1, off, 64);
            d2 += __shfl_xor(d2, off, 64);
            d3 += __shfl_xor(d3, off, 64);
        }
        const float e0 = __expf(d0), e1 = __expf(d1), e2 = __expf(d2), e3 = __expf(d3);
        sumexp += (e0 + e1) + (e2 + e3);
        acc.x += e0*x0.x + e1*x1.x + e2*x2.x + e3*x3.x;
        acc.y += e0*x0.y + e1*x1.y + e2*x2.y + e3*x3.y;
        acc.z += e0*x0.z + e1*x1.z + e2*x2.z + e3*x3.z;
        acc.w += e0*x0.w + e1*x1.w + e2*x2.w + e3*x3.w;
    }
    // remainder (< 4 rows for this wave)
    for (; i < end; i += 4) {
        const f4 xv = __builtin_nontemporal_load((const f4*)(x + (size_t)i * DIM) + lane);
        float d = xv.x*wv.x + xv.y*wv.y + xv.z*wv.z + xv.w*wv.w;
        d = wave_allreduce(d);
        const float e = __expf(d);
        sumexp += e;
        acc.x += e*xv.x; acc.y += e*xv.y; acc.z += e*xv.z; acc.w += e*xv.w;
    }

    // combine the 4 waves' partials in LDS
    __shared__ f4    s_acc[256];
    __shared__ float s_sum[4];
    s_acc[threadIdx.x] = acc;
    if (lane == 0) s_sum[wave] = sumexp;   // wave-uniform after butterfly
    __syncthreads();

    if (wave == 0) {
        f4 a = s_acc[lane];
        const f4 b = s_acc[64 + lane];
        const f4 c = s_acc[128 + lane];
        const f4 d4 = s_acc[192 + lane];
        a.x += b.x + c.x + d4.x;
        a.y += b.y + c.y + d4.y;
        a.z += b.z + c.z + d4.z;
        a.w += b.w + c.w + d4.w;
        ((f4*)(out + (size_t)seg * DIM))[lane] = a;   // unnormalized
        if (lane == 0)
            atomicAdd(total, (s_sum[0] + s_sum[1]) + (s_sum[2] + s_sum[3]));
    }
}

__global__ __launch_bounds__(256) void attnpool_scale(
    float* __restrict__ out, const float* __restrict__ total)
{
    const float inv = 1.0f / *total;
    const int idx = blockIdx.x * 256 + threadIdx.x;
    f4* p = (f4*)out + idx;
    f4 v = *p;
    v.x *= inv; v.y *= inv; v.z *= inv; v.w *= inv;
    *p = v;
}

extern "C" void kernel_launch(void* const* d_in, const int* in_sizes, int n_in,
                              void* d_out, int out_size, void* d_ws, size_t ws_size,
                              hipStream_t stream) {
    const float* x   = (const float*)d_in[0];
    const float* w   = (const float*)d_in[1];
    const int*  bidx = (const int*)d_in[2];
    const int n = in_sizes[2];          // N = 1,000,000
    float* out   = (float*)d_out;       // [NSEG, DIM]
    float* total = (float*)d_ws;        // global sum-of-exp accumulator

    hipMemsetAsync(total, 0, sizeof(float), stream);
    attnpool_acc<<<NSEG, 256, 0, stream>>>(x, w, bidx, n, out, total);
    attnpool_scale<<<(NSEG * DIM / 4) / 256, 256, 0, stream>>>(out, total);
}